// Round 1
// baseline (119.107 us; speedup 1.0000x reference)
//
#include <hip/hip_runtime.h>
#include <hip/hip_bf16.h>

#define NN 8192
#define D_IN 128
#define D_OUT 64
#define GAT_ALPHA 0.2f
#define LOG2E 1.4426950408889634f

typedef __attribute__((ext_vector_type(4))) float f32x4;
typedef __attribute__((ext_vector_type(8))) short short8;

static __device__ __forceinline__ unsigned short f32_bf16(float f) {
    unsigned u = __builtin_bit_cast(unsigned, f);
    u += 0x7fffu + ((u >> 16) & 1u);   // round-to-nearest-even
    return (unsigned short)(u >> 16);
}

// ---------------- Kernel 1: wh = h@w; wh1p/wh2p (x log2e); whT in bf16 ----------------
__global__ __launch_bounds__(256) void gat_prep(
    const float* __restrict__ h, const float* __restrict__ w,
    const float* __restrict__ a,
    unsigned short* __restrict__ whT, float* __restrict__ wh1p,
    float* __restrict__ wh2p)
{
    __shared__ float hs[16 * 128];
    __shared__ float whs[16][64];
    const int t = threadIdx.x;
    const int i0 = blockIdx.x * 16;

    // stage 16x128 h tile (contiguous 2048 floats)
    const float* hsrc = h + (size_t)i0 * D_IN;
    *(float4*)(hs + t * 8)     = *(const float4*)(hsrc + t * 8);
    *(float4*)(hs + t * 8 + 4) = *(const float4*)(hsrc + t * 8 + 4);
    __syncthreads();

    const int r  = t >> 4;          // local row 0..15
    const int og = (t & 15) * 4;    // 4 output dims
    f32x4 acc = {0.f, 0.f, 0.f, 0.f};
    for (int k = 0; k < D_IN; ++k) {
        float hv = hs[r * 128 + k];                       // LDS broadcast
        float4 wv = *(const float4*)(w + k * D_OUT + og); // L1/L2 hot
        acc[0] += hv * wv.x; acc[1] += hv * wv.y;
        acc[2] += hv * wv.z; acc[3] += hv * wv.w;
    }
    whs[r][og]     = acc[0];
    whs[r][og + 1] = acc[1];
    whs[r][og + 2] = acc[2];
    whs[r][og + 3] = acc[3];

    // attention projections: wh1 = wh@a[:64], wh2 = wh@a[64:], fold log2(e)
    float p1 = acc[0]*a[og] + acc[1]*a[og+1] + acc[2]*a[og+2] + acc[3]*a[og+3];
    float p2 = acc[0]*a[64+og] + acc[1]*a[64+og+1] + acc[2]*a[64+og+2] + acc[3]*a[64+og+3];
    #pragma unroll
    for (int m = 1; m < 16; m <<= 1) {
        p1 += __shfl_xor(p1, m);
        p2 += __shfl_xor(p2, m);
    }
    if ((t & 15) == 0) {
        wh1p[i0 + r] = p1 * LOG2E;
        wh2p[i0 + r] = p2 * LOG2E;
    }
    __syncthreads();

    // transposed bf16 store: whT[o][i0..i0+15]
    {
        const int o = t >> 2, q = t & 3;
        ushort4 v;
        v.x = f32_bf16(whs[q * 4 + 0][o]);
        v.y = f32_bf16(whs[q * 4 + 1][o]);
        v.z = f32_bf16(whs[q * 4 + 2][o]);
        v.w = f32_bf16(whs[q * 4 + 3][o]);
        *(ushort4*)(whT + (size_t)o * NN + i0 + q * 4) = v;
    }
}

// ---------------- Kernel 2: fused mask+softmax+att@wh+bias+elu ----------------
// 512 blocks x 512 threads. Block owns 16 rows; wave w owns j in [w*1024,(w+1)*1024).
__global__ __launch_bounds__(512) void gat_main(
    const int* __restrict__ adj, const unsigned short* __restrict__ whT,
    const float* __restrict__ wh1p, const float* __restrict__ wh2p,
    const float* __restrict__ bias, float* __restrict__ out)
{
    __shared__ float nums8[8][16][64];
    __shared__ float dens8[8][16];

    const int t    = threadIdx.x;
    const int wv   = t >> 6;        // wave 0..7
    const int lane = t & 63;
    const int il   = lane & 15;     // i-local (A rows) and n-local (B cols)
    const int kg   = lane >> 4;     // k-group 0..3
    const int i0   = blockIdx.x * 16;
    const int row  = i0 + il;

    const float c = wh1p[row];
    const int* adj_row = adj + (size_t)row * NN;

    f32x4 acc0 = {0,0,0,0}, acc1 = {0,0,0,0}, acc2 = {0,0,0,0}, acc3 = {0,0,0,0};
    float den = 0.f;

    const unsigned short* bt0 = whT + (size_t)(0 * 16 + il) * NN;
    const unsigned short* bt1 = whT + (size_t)(1 * 16 + il) * NN;
    const unsigned short* bt2 = whT + (size_t)(2 * 16 + il) * NN;
    const unsigned short* bt3 = whT + (size_t)(3 * 16 + il) * NN;

    const int jbeg = wv * (NN / 8);
    for (int j0 = jbeg; j0 < jbeg + (NN / 8); j0 += 32) {
        const int jb = j0 + kg * 8;
        int4   ad0 = *(const int4*)(adj_row + jb);
        int4   ad1 = *(const int4*)(adj_row + jb + 4);
        float4 w20 = *(const float4*)(wh2p + jb);
        float4 w21 = *(const float4*)(wh2p + jb + 4);

        short8 af;
        {
            float x, p;
            x = c + w20.x; x = fmaxf(x, GAT_ALPHA * x); p = __builtin_amdgcn_exp2f(x);
            p = ad0.x ? p : 0.f; den += p; af[0] = (short)f32_bf16(p);
            x = c + w20.y; x = fmaxf(x, GAT_ALPHA * x); p = __builtin_amdgcn_exp2f(x);
            p = ad0.y ? p : 0.f; den += p; af[1] = (short)f32_bf16(p);
            x = c + w20.z; x = fmaxf(x, GAT_ALPHA * x); p = __builtin_amdgcn_exp2f(x);
            p = ad0.z ? p : 0.f; den += p; af[2] = (short)f32_bf16(p);
            x = c + w20.w; x = fmaxf(x, GAT_ALPHA * x); p = __builtin_amdgcn_exp2f(x);
            p = ad0.w ? p : 0.f; den += p; af[3] = (short)f32_bf16(p);
            x = c + w21.x; x = fmaxf(x, GAT_ALPHA * x); p = __builtin_amdgcn_exp2f(x);
            p = ad1.x ? p : 0.f; den += p; af[4] = (short)f32_bf16(p);
            x = c + w21.y; x = fmaxf(x, GAT_ALPHA * x); p = __builtin_amdgcn_exp2f(x);
            p = ad1.y ? p : 0.f; den += p; af[5] = (short)f32_bf16(p);
            x = c + w21.z; x = fmaxf(x, GAT_ALPHA * x); p = __builtin_amdgcn_exp2f(x);
            p = ad1.z ? p : 0.f; den += p; af[6] = (short)f32_bf16(p);
            x = c + w21.w; x = fmaxf(x, GAT_ALPHA * x); p = __builtin_amdgcn_exp2f(x);
            p = ad1.w ? p : 0.f; den += p; af[7] = (short)f32_bf16(p);
        }

        short8 b0 = *(const short8*)(bt0 + jb);
        short8 b1 = *(const short8*)(bt1 + jb);
        short8 b2 = *(const short8*)(bt2 + jb);
        short8 b3 = *(const short8*)(bt3 + jb);

        acc0 = __builtin_amdgcn_mfma_f32_16x16x32_bf16(af, b0, acc0, 0, 0, 0);
        acc1 = __builtin_amdgcn_mfma_f32_16x16x32_bf16(af, b1, acc1, 0, 0, 0);
        acc2 = __builtin_amdgcn_mfma_f32_16x16x32_bf16(af, b2, acc2, 0, 0, 0);
        acc3 = __builtin_amdgcn_mfma_f32_16x16x32_bf16(af, b3, acc3, 0, 0, 0);
    }

    // deterministic cross-wave reduction
    den += __shfl_xor(den, 16);
    den += __shfl_xor(den, 32);
    if (kg == 0) dens8[wv][il] = den;

    // D layout: row = kg*4 + reg, col = nt*16 + il
    #pragma unroll
    for (int q = 0; q < 4; ++q) {
        nums8[wv][kg * 4 + q][0 * 16 + il] = acc0[q];
        nums8[wv][kg * 4 + q][1 * 16 + il] = acc1[q];
        nums8[wv][kg * 4 + q][2 * 16 + il] = acc2[q];
        nums8[wv][kg * 4 + q][3 * 16 + il] = acc3[q];
    }
    __syncthreads();

    // epilogue: 1024 outputs, 512 threads
    for (int idx = t; idx < 16 * 64; idx += 512) {
        const int rr = idx >> 6, cc = idx & 63;
        float s = 0.f, d = 0.f;
        #pragma unroll
        for (int wq = 0; wq < 8; ++wq) { s += nums8[wq][rr][cc]; d += dens8[wq][rr]; }
        float val = s / d + bias[cc];
        out[(size_t)(i0 + rr) * D_OUT + cc] =
            val > 0.f ? val : (__builtin_amdgcn_exp2f(val * LOG2E) - 1.f);
    }
}

extern "C" void kernel_launch(void* const* d_in, const int* in_sizes, int n_in,
                              void* d_out, int out_size, void* d_ws, size_t ws_size,
                              hipStream_t stream) {
    const float* h   = (const float*)d_in[0];
    const int*   adj = (const int*)d_in[1];
    const float* w   = (const float*)d_in[2];
    const float* a   = (const float*)d_in[3];
    const float* b   = (const float*)d_in[4];
    float* out = (float*)d_out;

    char* ws = (char*)d_ws;
    unsigned short* whT = (unsigned short*)ws;                       // 64*8192*2 = 1 MB
    float* wh1p = (float*)(ws + (size_t)D_OUT * NN * 2);             // 32 KB
    float* wh2p = (float*)(ws + (size_t)D_OUT * NN * 2 + NN * 4);    // 32 KB

    gat_prep<<<NN / 16, 256, 0, stream>>>(h, w, a, whT, wh1p, wh2p);
    gat_main<<<NN / 16, 512, 0, stream>>>(adj, whT, wh1p, wh2p, b, out);
}

// Round 2
// 77.922 us; speedup vs baseline: 1.5285x; 1.5285x over previous
//
#include <hip/hip_runtime.h>
#include <hip/hip_bf16.h>

#define NN 8192
#define D_IN 128
#define D_OUT 64
#define GAT_ALPHA 0.2f
#define LOG2E 1.4426950408889634f
#define JT 256
#define NTILES (NN / JT)

typedef __attribute__((ext_vector_type(4))) float f32x4;
typedef __attribute__((ext_vector_type(8))) short short8;

static __device__ __forceinline__ unsigned short f32_bf16(float f) {
    unsigned u = __builtin_bit_cast(unsigned, f);
    u += 0x7fffu + ((u >> 16) & 1u);   // round-to-nearest-even
    return (unsigned short)(u >> 16);
}

// ---- Kernel 1: wh = h@w; wh1p/wh2p (x log2e); whB = K-blocked bf16 wh^T ----
// whB[j>>3][dim][j&7]: element (dim, j) at whB[(j>>3)*512 + dim*8 + (j&7)]
__global__ __launch_bounds__(256) void gat_prep(
    const float* __restrict__ h, const float* __restrict__ w,
    const float* __restrict__ a,
    unsigned short* __restrict__ whB, float* __restrict__ wh1p,
    float* __restrict__ wh2p)
{
    __shared__ float hs[16 * 128];
    __shared__ float whs[16][64];
    const int t = threadIdx.x;
    const int i0 = blockIdx.x * 16;

    const float* hsrc = h + (size_t)i0 * D_IN;
    *(float4*)(hs + t * 8)     = *(const float4*)(hsrc + t * 8);
    *(float4*)(hs + t * 8 + 4) = *(const float4*)(hsrc + t * 8 + 4);
    __syncthreads();

    const int r  = t >> 4;          // local row 0..15
    const int og = (t & 15) * 4;    // 4 output dims
    f32x4 acc = {0.f, 0.f, 0.f, 0.f};
    for (int k = 0; k < D_IN; ++k) {
        float hv = hs[r * 128 + k];
        float4 wv = *(const float4*)(w + k * D_OUT + og);
        acc[0] += hv * wv.x; acc[1] += hv * wv.y;
        acc[2] += hv * wv.z; acc[3] += hv * wv.w;
    }
    whs[r][og]     = acc[0];
    whs[r][og + 1] = acc[1];
    whs[r][og + 2] = acc[2];
    whs[r][og + 3] = acc[3];

    float p1 = acc[0]*a[og] + acc[1]*a[og+1] + acc[2]*a[og+2] + acc[3]*a[og+3];
    float p2 = acc[0]*a[64+og] + acc[1]*a[64+og+1] + acc[2]*a[64+og+2] + acc[3]*a[64+og+3];
    #pragma unroll
    for (int m = 1; m < 16; m <<= 1) {
        p1 += __shfl_xor(p1, m);
        p2 += __shfl_xor(p2, m);
    }
    if ((t & 15) == 0) {
        wh1p[i0 + r] = p1 * LOG2E;
        wh2p[i0 + r] = p2 * LOG2E;
    }
    __syncthreads();

    // K-blocked bf16 store: two 8-j blocks (jb8 = i0/8, i0/8+1)
    {
        const int half = t >> 7;         // which 8-row group
        const int dim  = (t >> 1) & 63;
        const int e0   = (t & 1) * 4;
        ushort4 v;
        v.x = f32_bf16(whs[half * 8 + e0 + 0][dim]);
        v.y = f32_bf16(whs[half * 8 + e0 + 1][dim]);
        v.z = f32_bf16(whs[half * 8 + e0 + 2][dim]);
        v.w = f32_bf16(whs[half * 8 + e0 + 3][dim]);
        *(ushort4*)(whB + (size_t)(i0 / 8 + half) * 512 + dim * 8 + e0) = v;
    }
}

// ---- Kernel 2: fused mask+softmax+att@wh+bias+elu, LDS-staged adj ----
__global__ __launch_bounds__(512) void gat_main(
    const int* __restrict__ adj, const unsigned short* __restrict__ whB,
    const float* __restrict__ wh1p, const float* __restrict__ wh2p,
    const float* __restrict__ bias, float* __restrict__ out)
{
    __shared__ alignas(16) int adjs[2][16][260];   // +4 pad -> 2-way aliasing (free)
    __shared__ float nums8[8][16][64];
    __shared__ float dens8[8][16];

    const int t    = threadIdx.x;
    const int wv   = t >> 6;        // wave 0..7
    const int lane = t & 63;
    const int il   = lane & 15;
    const int kg   = lane >> 4;
    const int i0   = blockIdx.x * 16;

    const float c = wh1p[i0 + il];

    f32x4 acc0 = {0,0,0,0}, acc1 = {0,0,0,0}, acc2 = {0,0,0,0}, acc3 = {0,0,0,0};
    float den = 0.f;

    const int r0 = wv * 2;          // this wave stages rows r0, r0+1

    // prologue: stage tile 0 (each wave: two 1KB contiguous row segments)
    {
        const int* g0 = adj + (size_t)(i0 + r0) * NN + lane * 4;
        const int* g1 = adj + (size_t)(i0 + r0 + 1) * NN + lane * 4;
        __builtin_amdgcn_global_load_lds(
            (const __attribute__((address_space(1))) void*)g0,
            (__attribute__((address_space(3))) void*)&adjs[0][r0][0], 16, 0, 0);
        __builtin_amdgcn_global_load_lds(
            (const __attribute__((address_space(1))) void*)g1,
            (__attribute__((address_space(3))) void*)&adjs[0][r0 + 1][0], 16, 0, 0);
    }

    for (int tg = 0; tg < NTILES; ++tg) {
        const int b = tg & 1;
        __syncthreads();            // drains own stage(tg); all waves' buf b valid

        if (tg + 1 < NTILES) {      // prefetch tile tg+1 into other buffer
            const int jn = (tg + 1) * JT;
            const int* g0 = adj + (size_t)(i0 + r0) * NN + jn + lane * 4;
            const int* g1 = adj + (size_t)(i0 + r0 + 1) * NN + jn + lane * 4;
            __builtin_amdgcn_global_load_lds(
                (const __attribute__((address_space(1))) void*)g0,
                (__attribute__((address_space(3))) void*)&adjs[b ^ 1][r0][0], 16, 0, 0);
            __builtin_amdgcn_global_load_lds(
                (const __attribute__((address_space(1))) void*)g1,
                (__attribute__((address_space(3))) void*)&adjs[b ^ 1][r0 + 1][0], 16, 0, 0);
        }

        // compute: wave wv handles cols [wv*32, wv*32+32) of this tile
        const int jl = wv * 32 + kg * 8;
        const int jg = tg * JT + jl;
        int4 ad0 = *(const int4*)&adjs[b][il][jl];
        int4 ad1 = *(const int4*)&adjs[b][il][jl + 4];
        float4 w20 = *(const float4*)(wh2p + jg);
        float4 w21 = *(const float4*)(wh2p + jg + 4);

        const unsigned short* bb =
            whB + (size_t)(tg * 32 + wv * 4 + kg) * 512 + il * 8;
        short8 b0 = *(const short8*)(bb);
        short8 b1 = *(const short8*)(bb + 128);
        short8 b2 = *(const short8*)(bb + 256);
        short8 b3 = *(const short8*)(bb + 384);

        short8 af;
        {
            float x, p;
            x = c + w20.x; x = fmaxf(x, GAT_ALPHA * x); p = __builtin_amdgcn_exp2f(x);
            p = ad0.x ? p : 0.f; den += p; af[0] = (short)f32_bf16(p);
            x = c + w20.y; x = fmaxf(x, GAT_ALPHA * x); p = __builtin_amdgcn_exp2f(x);
            p = ad0.y ? p : 0.f; den += p; af[1] = (short)f32_bf16(p);
            x = c + w20.z; x = fmaxf(x, GAT_ALPHA * x); p = __builtin_amdgcn_exp2f(x);
            p = ad0.z ? p : 0.f; den += p; af[2] = (short)f32_bf16(p);
            x = c + w20.w; x = fmaxf(x, GAT_ALPHA * x); p = __builtin_amdgcn_exp2f(x);
            p = ad0.w ? p : 0.f; den += p; af[3] = (short)f32_bf16(p);
            x = c + w21.x; x = fmaxf(x, GAT_ALPHA * x); p = __builtin_amdgcn_exp2f(x);
            p = ad1.x ? p : 0.f; den += p; af[4] = (short)f32_bf16(p);
            x = c + w21.y; x = fmaxf(x, GAT_ALPHA * x); p = __builtin_amdgcn_exp2f(x);
            p = ad1.y ? p : 0.f; den += p; af[5] = (short)f32_bf16(p);
            x = c + w21.z; x = fmaxf(x, GAT_ALPHA * x); p = __builtin_amdgcn_exp2f(x);
            p = ad1.z ? p : 0.f; den += p; af[6] = (short)f32_bf16(p);
            x = c + w21.w; x = fmaxf(x, GAT_ALPHA * x); p = __builtin_amdgcn_exp2f(x);
            p = ad1.w ? p : 0.f; den += p; af[7] = (short)f32_bf16(p);
        }

        acc0 = __builtin_amdgcn_mfma_f32_16x16x32_bf16(af, b0, acc0, 0, 0, 0);
        acc1 = __builtin_amdgcn_mfma_f32_16x16x32_bf16(af, b1, acc1, 0, 0, 0);
        acc2 = __builtin_amdgcn_mfma_f32_16x16x32_bf16(af, b2, acc2, 0, 0, 0);
        acc3 = __builtin_amdgcn_mfma_f32_16x16x32_bf16(af, b3, acc3, 0, 0, 0);
    }

    // deterministic cross-wave reduction
    den += __shfl_xor(den, 16);
    den += __shfl_xor(den, 32);
    if (kg == 0) dens8[wv][il] = den;

    #pragma unroll
    for (int q = 0; q < 4; ++q) {
        nums8[wv][kg * 4 + q][0 * 16 + il] = acc0[q];
        nums8[wv][kg * 4 + q][1 * 16 + il] = acc1[q];
        nums8[wv][kg * 4 + q][2 * 16 + il] = acc2[q];
        nums8[wv][kg * 4 + q][3 * 16 + il] = acc3[q];
    }
    __syncthreads();

    for (int idx = t; idx < 16 * 64; idx += 512) {
        const int rr = idx >> 6, cc = idx & 63;
        float s = 0.f, d = 0.f;
        #pragma unroll
        for (int wq = 0; wq < 8; ++wq) { s += nums8[wq][rr][cc]; d += dens8[wq][rr]; }
        float val = s / d + bias[cc];
        out[(size_t)(i0 + rr) * D_OUT + cc] =
            val > 0.f ? val : (__builtin_amdgcn_exp2f(val * LOG2E) - 1.f);
    }
}

extern "C" void kernel_launch(void* const* d_in, const int* in_sizes, int n_in,
                              void* d_out, int out_size, void* d_ws, size_t ws_size,
                              hipStream_t stream) {
    const float* h   = (const float*)d_in[0];
    const int*   adj = (const int*)d_in[1];
    const float* w   = (const float*)d_in[2];
    const float* a   = (const float*)d_in[3];
    const float* b   = (const float*)d_in[4];
    float* out = (float*)d_out;

    char* ws = (char*)d_ws;
    unsigned short* whB = (unsigned short*)ws;                       // 64*8192*2 = 1 MB
    float* wh1p = (float*)(ws + (size_t)D_OUT * NN * 2);             // 32 KB
    float* wh2p = (float*)(ws + (size_t)D_OUT * NN * 2 + NN * 4);    // 32 KB

    gat_prep<<<NN / 16, 256, 0, stream>>>(h, w, a, whB, wh1p, wh2p);
    gat_main<<<NN / 16, 512, 0, stream>>>(adj, whB, wh1p, wh2p, b, out);
}

// Round 3
// 77.646 us; speedup vs baseline: 1.5340x; 1.0036x over previous
//
#include <hip/hip_runtime.h>
#include <hip/hip_bf16.h>

#define NN 8192
#define D_IN 128
#define D_OUT 64
#define GAT_ALPHA 0.2f
#define LOG2E 1.4426950408889634f

typedef __attribute__((ext_vector_type(4))) float f32x4;
typedef __attribute__((ext_vector_type(8))) short short8;

static __device__ __forceinline__ unsigned short f32_bf16(float f) {
    unsigned u = __builtin_bit_cast(unsigned, f);
    u += 0x7fffu + ((u >> 16) & 1u);   // round-to-nearest-even
    return (unsigned short)(u >> 16);
}

// ---- Kernel 1: wh = h@w; wh1p/wh2p (x log2e); whB = K-blocked bf16 wh^T ----
// whB[j>>3][dim][j&7]: element (dim, j) at whB[(j>>3)*512 + dim*8 + (j&7)]
__global__ __launch_bounds__(256) void gat_prep(
    const float* __restrict__ h, const float* __restrict__ w,
    const float* __restrict__ a,
    unsigned short* __restrict__ whB, float* __restrict__ wh1p,
    float* __restrict__ wh2p)
{
    __shared__ float hs[16 * 128];
    __shared__ float whs[16][64];
    const int t = threadIdx.x;
    const int i0 = blockIdx.x * 16;

    const float* hsrc = h + (size_t)i0 * D_IN;
    *(float4*)(hs + t * 8)     = *(const float4*)(hsrc + t * 8);
    *(float4*)(hs + t * 8 + 4) = *(const float4*)(hsrc + t * 8 + 4);
    __syncthreads();

    const int r  = t >> 4;          // local row 0..15
    const int og = (t & 15) * 4;    // 4 output dims
    f32x4 acc = {0.f, 0.f, 0.f, 0.f};
    for (int k = 0; k < D_IN; ++k) {
        float hv = hs[r * 128 + k];
        float4 wv = *(const float4*)(w + k * D_OUT + og);
        acc[0] += hv * wv.x; acc[1] += hv * wv.y;
        acc[2] += hv * wv.z; acc[3] += hv * wv.w;
    }
    whs[r][og]     = acc[0];
    whs[r][og + 1] = acc[1];
    whs[r][og + 2] = acc[2];
    whs[r][og + 3] = acc[3];

    float p1 = acc[0]*a[og] + acc[1]*a[og+1] + acc[2]*a[og+2] + acc[3]*a[og+3];
    float p2 = acc[0]*a[64+og] + acc[1]*a[64+og+1] + acc[2]*a[64+og+2] + acc[3]*a[64+og+3];
    #pragma unroll
    for (int m = 1; m < 16; m <<= 1) {
        p1 += __shfl_xor(p1, m);
        p2 += __shfl_xor(p2, m);
    }
    if ((t & 15) == 0) {
        wh1p[i0 + r] = p1 * LOG2E;
        wh2p[i0 + r] = p2 * LOG2E;
    }
    __syncthreads();

    {
        const int half = t >> 7;         // which 8-row group
        const int dim  = (t >> 1) & 63;
        const int e0   = (t & 1) * 4;
        ushort4 v;
        v.x = f32_bf16(whs[half * 8 + e0 + 0][dim]);
        v.y = f32_bf16(whs[half * 8 + e0 + 1][dim]);
        v.z = f32_bf16(whs[half * 8 + e0 + 2][dim]);
        v.w = f32_bf16(whs[half * 8 + e0 + 3][dim]);
        *(ushort4*)(whB + (size_t)(i0 / 8 + half) * 512 + dim * 8 + e0) = v;
    }
}

// ---- Kernel 2: per-wave private pipeline, counted vmcnt, no loop barriers ----
// 512 blocks x 256 threads (4 waves). Block owns 16 rows; wave wv owns cols
// [wv*2048, (wv+1)*2048) in 64 tiles of 32 cols. LDS tile = 16 rows x 8 chunks
// of 16B, swizzled: unit(r,c) = r*8 + ((c+r)&7), applied on global src AND read.
#define AF_LANE(PV, AD, IDX)                                                    \
    do { float x_ = c + (PV);                                                   \
         x_ = fmaxf(x_, GAT_ALPHA * x_);                                        \
         float p_ = __builtin_amdgcn_exp2f(x_);                                 \
         p_ = (AD) ? p_ : 0.f; den += p_;                                       \
         af[IDX] = (short)f32_bf16(p_); } while (0)

#define TILE(n, WN, DO_STAGE) do {                                              \
    const int j0_ = jbase + (n) * 32;                                           \
    float4 w20 = *(const float4*)(wh2p + j0_ + kg * 8);                         \
    float4 w21 = *(const float4*)(wh2p + j0_ + kg * 8 + 4);                     \
    const unsigned short* bb_ = whB + (size_t)(j0_ / 8 + kg) * 512 + il * 8;    \
    short8 b0 = *(const short8*)(bb_);                                          \
    short8 b1 = *(const short8*)(bb_ + 128);                                    \
    short8 b2 = *(const short8*)(bb_ + 256);                                    \
    short8 b3 = *(const short8*)(bb_ + 384);                                    \
    __builtin_amdgcn_sched_barrier(0);                                          \
    if (DO_STAGE) {                                                             \
        const int tl_ = (n) + 3;                                                \
        const int off_ = tl_ * 32;                                              \
        __builtin_amdgcn_global_load_lds(                                       \
            (const __attribute__((address_space(1))) void*)(g0 + off_),         \
            (__attribute__((address_space(3))) void*)&adjs[wv][tl_ & 3][0],     \
            16, 0, 0);                                                          \
        __builtin_amdgcn_global_load_lds(                                       \
            (const __attribute__((address_space(1))) void*)(g1 + off_),         \
            (__attribute__((address_space(3))) void*)&adjs[wv][tl_ & 3][64],    \
            16, 0, 0);                                                          \
    }                                                                           \
    asm volatile("s_waitcnt vmcnt(" #WN ")" ::: "memory");                      \
    __builtin_amdgcn_sched_barrier(0);                                          \
    const int4* base_ = &adjs[wv][(n) & 3][0];                                  \
    int4 ad0 = base_[uA];                                                       \
    int4 ad1 = base_[uB];                                                       \
    short8 af;                                                                  \
    AF_LANE(w20.x, ad0.x, 0); AF_LANE(w20.y, ad0.y, 1);                         \
    AF_LANE(w20.z, ad0.z, 2); AF_LANE(w20.w, ad0.w, 3);                         \
    AF_LANE(w21.x, ad1.x, 4); AF_LANE(w21.y, ad1.y, 5);                         \
    AF_LANE(w21.z, ad1.z, 6); AF_LANE(w21.w, ad1.w, 7);                         \
    acc0 = __builtin_amdgcn_mfma_f32_16x16x32_bf16(af, b0, acc0, 0, 0, 0);      \
    acc1 = __builtin_amdgcn_mfma_f32_16x16x32_bf16(af, b1, acc1, 0, 0, 0);      \
    acc2 = __builtin_amdgcn_mfma_f32_16x16x32_bf16(af, b2, acc2, 0, 0, 0);      \
    acc3 = __builtin_amdgcn_mfma_f32_16x16x32_bf16(af, b3, acc3, 0, 0, 0);      \
} while (0)

__global__ __launch_bounds__(256) void gat_main(
    const int* __restrict__ adj, const unsigned short* __restrict__ whB,
    const float* __restrict__ wh1p, const float* __restrict__ wh2p,
    const float* __restrict__ bias, float* __restrict__ out)
{
    __shared__ int4  adjs[4][4][128];     // [wave][depth][16B unit] = 32 KB
    __shared__ float nums4[4][16][64];    // 16 KB
    __shared__ float dens4[4][16];

    const int t    = threadIdx.x;
    const int wv   = t >> 6;
    const int lane = t & 63;
    const int il   = lane & 15;
    const int kg   = lane >> 4;
    const int i0   = blockIdx.x * 16;
    const int jbase = wv * 2048;

    const float c = wh1p[i0 + il];

    // staging geometry: instr I covers rows I*8..I*8+7; lane l -> row l>>3,
    // chunk c = ((l&7) - (l>>3)) & 7 (inverse of unit(r,c)=r*8+((c+r)&7))
    const int srow = lane >> 3;
    const int scol = ((lane & 7) + 8 - srow) & 7;
    const int* g0 = adj + (size_t)(i0 + srow) * NN + jbase + scol * 4;
    const int* g1 = adj + (size_t)(i0 + 8 + srow) * NN + jbase + scol * 4;

    // read units for this lane (invariant across tiles)
    const int uA = il * 8 + ((2 * kg + il) & 7);
    const int uB = il * 8 + ((2 * kg + 1 + il) & 7);

    f32x4 acc0 = {0,0,0,0}, acc1 = {0,0,0,0}, acc2 = {0,0,0,0}, acc3 = {0,0,0,0};
    float den = 0.f;

    // prologue: stage tiles 0,1,2 (6 VMEM ops)
    #pragma unroll
    for (int tl = 0; tl < 3; ++tl) {
        const int off = tl * 32;
        __builtin_amdgcn_global_load_lds(
            (const __attribute__((address_space(1))) void*)(g0 + off),
            (__attribute__((address_space(3))) void*)&adjs[wv][tl][0], 16, 0, 0);
        __builtin_amdgcn_global_load_lds(
            (const __attribute__((address_space(1))) void*)(g1 + off),
            (__attribute__((address_space(3))) void*)&adjs[wv][tl][64], 16, 0, 0);
    }

    // peeled head (exact vmcnt counts: ops newer than stage(n) at the wait)
    TILE(0, 12, true);
    TILE(1, 18, true);
    for (int n = 2; n <= 60; ++n) {
        TILE(n, 24, true);
    }
    TILE(61, 22, false);
    TILE(62, 20, false);
    TILE(63, 18, false);

    // cross-wave reduction (deterministic)
    den += __shfl_xor(den, 16);
    den += __shfl_xor(den, 32);
    if (kg == 0) dens4[wv][il] = den;

    #pragma unroll
    for (int q = 0; q < 4; ++q) {
        nums4[wv][kg * 4 + q][0 * 16 + il] = acc0[q];
        nums4[wv][kg * 4 + q][1 * 16 + il] = acc1[q];
        nums4[wv][kg * 4 + q][2 * 16 + il] = acc2[q];
        nums4[wv][kg * 4 + q][3 * 16 + il] = acc3[q];
    }
    __syncthreads();

    for (int idx = t; idx < 16 * 64; idx += 256) {
        const int rr = idx >> 6, cc = idx & 63;
        float s = 0.f, d = 0.f;
        #pragma unroll
        for (int wq = 0; wq < 4; ++wq) { s += nums4[wq][rr][cc]; d += dens4[wq][rr]; }
        float val = s / d + bias[cc];
        out[(size_t)(i0 + rr) * D_OUT + cc] =
            val > 0.f ? val : (__builtin_amdgcn_exp2f(val * LOG2E) - 1.f);
    }
}

extern "C" void kernel_launch(void* const* d_in, const int* in_sizes, int n_in,
                              void* d_out, int out_size, void* d_ws, size_t ws_size,
                              hipStream_t stream) {
    const float* h   = (const float*)d_in[0];
    const int*   adj = (const int*)d_in[1];
    const float* w   = (const float*)d_in[2];
    const float* a   = (const float*)d_in[3];
    const float* b   = (const float*)d_in[4];
    float* out = (float*)d_out;

    char* ws = (char*)d_ws;
    unsigned short* whB = (unsigned short*)ws;                       // 1 MB
    float* wh1p = (float*)(ws + (size_t)D_OUT * NN * 2);             // 32 KB
    float* wh2p = (float*)(ws + (size_t)D_OUT * NN * 2 + NN * 4);    // 32 KB

    gat_prep<<<NN / 16, 256, 0, stream>>>(h, w, a, whB, wh1p, wh2p);
    gat_main<<<NN / 16, 256, 0, stream>>>(adj, whB, wh1p, wh2p, b, out);
}

// Round 4
// 75.942 us; speedup vs baseline: 1.5684x; 1.0224x over previous
//
#include <hip/hip_runtime.h>
#include <hip/hip_bf16.h>

#define NN 8192
#define D_IN 128
#define D_OUT 64
#define GAT_ALPHA 0.2f
#define LOG2E 1.4426950408889634f

typedef __attribute__((ext_vector_type(4))) float f32x4;
typedef __attribute__((ext_vector_type(8))) short short8;

static __device__ __forceinline__ unsigned short f32_bf16(float f) {
    unsigned u = __builtin_bit_cast(unsigned, f);
    u += 0x7fffu + ((u >> 16) & 1u);   // round-to-nearest-even
    return (unsigned short)(u >> 16);
}

// ---- Kernel 1: wh = h@w; wh1p/wh2p (x log2e); whB = K-blocked bf16 wh^T ----
// whB[j>>3][dim][j&7]: element (dim, j) at whB[(j>>3)*512 + dim*8 + (j&7)]
__global__ __launch_bounds__(256) void gat_prep(
    const float* __restrict__ h, const float* __restrict__ w,
    const float* __restrict__ a,
    unsigned short* __restrict__ whB, float* __restrict__ wh1p,
    float* __restrict__ wh2p)
{
    __shared__ float hs[16 * 128];
    __shared__ float whs[16][64];
    const int t = threadIdx.x;
    const int i0 = blockIdx.x * 16;

    const float* hsrc = h + (size_t)i0 * D_IN;
    *(float4*)(hs + t * 8)     = *(const float4*)(hsrc + t * 8);
    *(float4*)(hs + t * 8 + 4) = *(const float4*)(hsrc + t * 8 + 4);
    __syncthreads();

    const int r  = t >> 4;          // local row 0..15
    const int og = (t & 15) * 4;    // 4 output dims
    f32x4 acc = {0.f, 0.f, 0.f, 0.f};
    for (int k = 0; k < D_IN; ++k) {
        float hv = hs[r * 128 + k];
        float4 wv = *(const float4*)(w + k * D_OUT + og);
        acc[0] += hv * wv.x; acc[1] += hv * wv.y;
        acc[2] += hv * wv.z; acc[3] += hv * wv.w;
    }
    whs[r][og]     = acc[0];
    whs[r][og + 1] = acc[1];
    whs[r][og + 2] = acc[2];
    whs[r][og + 3] = acc[3];

    float p1 = acc[0]*a[og] + acc[1]*a[og+1] + acc[2]*a[og+2] + acc[3]*a[og+3];
    float p2 = acc[0]*a[64+og] + acc[1]*a[64+og+1] + acc[2]*a[64+og+2] + acc[3]*a[64+og+3];
    #pragma unroll
    for (int m = 1; m < 16; m <<= 1) {
        p1 += __shfl_xor(p1, m);
        p2 += __shfl_xor(p2, m);
    }
    if ((t & 15) == 0) {
        wh1p[i0 + r] = p1 * LOG2E;
        wh2p[i0 + r] = p2 * LOG2E;
    }
    __syncthreads();

    {
        const int half = t >> 7;         // which 8-row group
        const int dim  = (t >> 1) & 63;
        const int e0   = (t & 1) * 4;
        ushort4 v;
        v.x = f32_bf16(whs[half * 8 + e0 + 0][dim]);
        v.y = f32_bf16(whs[half * 8 + e0 + 1][dim]);
        v.z = f32_bf16(whs[half * 8 + e0 + 2][dim]);
        v.w = f32_bf16(whs[half * 8 + e0 + 3][dim]);
        *(ushort4*)(whB + (size_t)(i0 / 8 + half) * 512 + dim * 8 + e0) = v;
    }
}

// ---- Kernel 2: per-wave private pipeline; reg loads pipelined R=2 so the
// vmcnt FIFO is never force-drained; adj stages keep S=3 depth in flight ----
#define AF_LANE(PV, AD, IDX)                                                    \
    do { float x_ = c + (PV);                                                   \
         x_ = fmaxf(x_, GAT_ALPHA * x_);                                        \
         float p_ = __builtin_amdgcn_exp2f(x_);                                 \
         p_ = (AD) ? p_ : 0.f; den += p_;                                       \
         af[IDX] = (short)f32_bf16(p_); } while (0)

#define REG_LOAD(nn, B0,B1,B2,B3, W0,W1) do {                                   \
    const int jr_ = jbase + (nn) * 32;                                          \
    W0 = *(const float4*)(wh2p + jr_ + kg * 8);                                 \
    W1 = *(const float4*)(wh2p + jr_ + kg * 8 + 4);                             \
    const unsigned short* bb_ = whB + (size_t)(jr_ / 8 + kg) * 512 + il * 8;    \
    B0 = *(const short8*)(bb_);                                                 \
    B1 = *(const short8*)(bb_ + 128);                                           \
    B2 = *(const short8*)(bb_ + 256);                                           \
    B3 = *(const short8*)(bb_ + 384);                                           \
} while (0)

#define ITER(n, WN, DO_REG, DO_STAGE, B0,B1,B2,B3, W0,W1) do {                  \
    short8 nb0 = {}, nb1 = {}, nb2 = {}, nb3 = {};                              \
    float4 nw0 = {}, nw1 = {};                                                  \
    if (DO_REG) REG_LOAD((n) + 2, nb0, nb1, nb2, nb3, nw0, nw1);                \
    __builtin_amdgcn_sched_barrier(0);                                          \
    if (DO_STAGE) {                                                             \
        const int off_ = ((n) + 3) * 32;                                        \
        __builtin_amdgcn_global_load_lds(                                       \
            (const __attribute__((address_space(1))) void*)(g0 + off_),         \
            (__attribute__((address_space(3))) void*)&adjs[wv][((n)+3) & 3][0], \
            16, 0, 0);                                                          \
        __builtin_amdgcn_global_load_lds(                                       \
            (const __attribute__((address_space(1))) void*)(g1 + off_),         \
            (__attribute__((address_space(3))) void*)&adjs[wv][((n)+3) & 3][64],\
            16, 0, 0);                                                          \
    }                                                                           \
    asm volatile("s_waitcnt vmcnt(" #WN ")" ::: "memory");                      \
    __builtin_amdgcn_sched_barrier(0);                                          \
    const int4* base_ = &adjs[wv][(n) & 3][0];                                  \
    int4 ad0 = base_[uA];                                                       \
    int4 ad1 = base_[uB];                                                       \
    short8 af;                                                                  \
    AF_LANE(W0.x, ad0.x, 0); AF_LANE(W0.y, ad0.y, 1);                           \
    AF_LANE(W0.z, ad0.z, 2); AF_LANE(W0.w, ad0.w, 3);                           \
    AF_LANE(W1.x, ad1.x, 4); AF_LANE(W1.y, ad1.y, 5);                           \
    AF_LANE(W1.z, ad1.z, 6); AF_LANE(W1.w, ad1.w, 7);                           \
    acc0 = __builtin_amdgcn_mfma_f32_16x16x32_bf16(af, B0, acc0, 0, 0, 0);      \
    acc1 = __builtin_amdgcn_mfma_f32_16x16x32_bf16(af, B1, acc1, 0, 0, 0);      \
    acc2 = __builtin_amdgcn_mfma_f32_16x16x32_bf16(af, B2, acc2, 0, 0, 0);      \
    acc3 = __builtin_amdgcn_mfma_f32_16x16x32_bf16(af, B3, acc3, 0, 0, 0);      \
    if (DO_REG) { B0 = nb0; B1 = nb1; B2 = nb2; B3 = nb3; W0 = nw0; W1 = nw1; } \
} while (0)

__global__ __launch_bounds__(256) void gat_main(
    const int* __restrict__ adj, const unsigned short* __restrict__ whB,
    const float* __restrict__ wh1p, const float* __restrict__ wh2p,
    const float* __restrict__ bias, float* __restrict__ out)
{
    __shared__ int4  adjs[4][4][128];     // [wave][depth][16B unit] = 32 KB
    __shared__ float nums4[4][16][64];    // 16 KB
    __shared__ float dens4[4][16];

    const int t    = threadIdx.x;
    const int wv   = t >> 6;
    const int lane = t & 63;
    const int il   = lane & 15;
    const int kg   = lane >> 4;
    const int i0   = blockIdx.x * 16;
    const int jbase = wv * 2048;

    const float c = wh1p[i0 + il];

    // staging geometry: lane l -> row l>>3, chunk ((l&7) - row) & 7
    // (inverse of LDS unit(r,c) = r*8 + ((c+r)&7))
    const int srow = lane >> 3;
    const int scol = ((lane & 7) + 8 - srow) & 7;
    const int* g0 = adj + (size_t)(i0 + srow) * NN + jbase + scol * 4;
    const int* g1 = adj + (size_t)(i0 + 8 + srow) * NN + jbase + scol * 4;

    // swizzled read units for this lane (invariant across tiles)
    const int uA = il * 8 + ((2 * kg + il) & 7);
    const int uB = il * 8 + ((2 * kg + 1 + il) & 7);

    f32x4 acc0 = {0,0,0,0}, acc1 = {0,0,0,0}, acc2 = {0,0,0,0}, acc3 = {0,0,0,0};
    float den = 0.f;

    // prologue: stage tiles 0,1,2 (6 VMEM), then reg-preload tiles 0,1 (12 VMEM)
    #pragma unroll
    for (int tl = 0; tl < 3; ++tl) {
        const int off = tl * 32;
        __builtin_amdgcn_global_load_lds(
            (const __attribute__((address_space(1))) void*)(g0 + off),
            (__attribute__((address_space(3))) void*)&adjs[wv][tl][0], 16, 0, 0);
        __builtin_amdgcn_global_load_lds(
            (const __attribute__((address_space(1))) void*)(g1 + off),
            (__attribute__((address_space(3))) void*)&adjs[wv][tl][64], 16, 0, 0);
    }
    short8 bA0, bA1, bA2, bA3; float4 wA0, wA1;   // even tiles
    short8 bB0, bB1, bB2, bB3; float4 wB0, wB1;   // odd tiles
    REG_LOAD(0, bA0, bA1, bA2, bA3, wA0, wA1);
    REG_LOAD(1, bB0, bB1, bB2, bB3, wB0, wB1);

    // peeled head (exact newer-op counts at each wait)
    ITER(0, 24, 1, 1, bA0, bA1, bA2, bA3, wA0, wA1);
    ITER(1, 30, 1, 1, bB0, bB1, bB2, bB3, wB0, wB1);
    ITER(2, 36, 1, 1, bA0, bA1, bA2, bA3, wA0, wA1);
    ITER(3, 24, 1, 1, bB0, bB1, bB2, bB3, wB0, wB1);

    #pragma clang loop unroll_count(1)
    for (int n = 4; n <= 58; n += 2) {
        ITER(n,     24, 1, 1, bA0, bA1, bA2, bA3, wA0, wA1);
        ITER(n + 1, 24, 1, 1, bB0, bB1, bB2, bB3, wB0, wB1);
    }

    ITER(60, 24, 1, 1, bA0, bA1, bA2, bA3, wA0, wA1);
    ITER(61, 22, 1, 0, bB0, bB1, bB2, bB3, wB0, wB1);
    ITER(62, 14, 0, 0, bA0, bA1, bA2, bA3, wA0, wA1);
    ITER(63,  6, 0, 0, bB0, bB1, bB2, bB3, wB0, wB1);

    // deterministic cross-wave reduction
    den += __shfl_xor(den, 16);
    den += __shfl_xor(den, 32);
    if (kg == 0) dens4[wv][il] = den;

    #pragma unroll
    for (int q = 0; q < 4; ++q) {
        nums4[wv][kg * 4 + q][0 * 16 + il] = acc0[q];
        nums4[wv][kg * 4 + q][1 * 16 + il] = acc1[q];
        nums4[wv][kg * 4 + q][2 * 16 + il] = acc2[q];
        nums4[wv][kg * 4 + q][3 * 16 + il] = acc3[q];
    }
    __syncthreads();

    for (int idx = t; idx < 16 * 64; idx += 256) {
        const int rr = idx >> 6, cc = idx & 63;
        float s = 0.f, d = 0.f;
        #pragma unroll
        for (int wq = 0; wq < 4; ++wq) { s += nums4[wq][rr][cc]; d += dens4[wq][rr]; }
        float val = s / d + bias[cc];
        out[(size_t)(i0 + rr) * D_OUT + cc] =
            val > 0.f ? val : (__builtin_amdgcn_exp2f(val * LOG2E) - 1.f);
    }
}

extern "C" void kernel_launch(void* const* d_in, const int* in_sizes, int n_in,
                              void* d_out, int out_size, void* d_ws, size_t ws_size,
                              hipStream_t stream) {
    const float* h   = (const float*)d_in[0];
    const int*   adj = (const int*)d_in[1];
    const float* w   = (const float*)d_in[2];
    const float* a   = (const float*)d_in[3];
    const float* b   = (const float*)d_in[4];
    float* out = (float*)d_out;

    char* ws = (char*)d_ws;
    unsigned short* whB = (unsigned short*)ws;                       // 1 MB
    float* wh1p = (float*)(ws + (size_t)D_OUT * NN * 2);             // 32 KB
    float* wh2p = (float*)(ws + (size_t)D_OUT * NN * 2 + NN * 4);    // 32 KB

    gat_prep<<<NN / 16, 256, 0, stream>>>(h, w, a, whB, wh1p, wh2p);
    gat_main<<<NN / 16, 256, 0, stream>>>(adj, whB, wh1p, wh2p, b, out);
}